// Round 7
// baseline (220.992 us; speedup 1.0000x reference)
//
#include <hip/hip_runtime.h>
#include <hip/hip_bf16.h>
#include <math.h>

#define N_NODES 50000
#define N_EDGES 800000
#define GEMM_ROWS 32
#define AGG_NODES 32
#define PAD_EDGES (N_EDGES + N_NODES * 15)  // segments padded to x16
#define SCAN_BLOCKS 49                      // ceil(50000 / 1024)
// 0.125 (1/sqrt(64)) * log2(e): folded into Wt -> exp2 in the hot loop.
#define SCALE_FOLD 0.18033688011112042f

typedef __attribute__((ext_vector_type(8))) short bf16x8_t;
typedef __attribute__((ext_vector_type(4))) float f32x4_t;

static __device__ __forceinline__ ushort bfrn(float v) {
  __hip_bfloat16 b = __float2bfloat16(v);  // round-to-nearest-even
  return __builtin_bit_cast(ushort, b);
}
static __device__ __forceinline__ uint packbf(float v) {  // hi | lo<<16
  ushort h = bfrn(v);
  float r = v - __uint_as_float((uint)h << 16);
  return (uint)h | ((uint)bfrn(r) << 16);
}
static __device__ __forceinline__ bf16x8_t as_bf16x8(uint4 u) {
  union { uint4 a; bf16x8_t b; } c; c.a = u; return c.b;
}
static __device__ __forceinline__ bf16x8_t as_bf16x8w(uint w0, uint w1,
                                                     uint w2, uint w3) {
  union { uint4 a; bf16x8_t b; } c; c.a = make_uint4(w0, w1, w2, w3); return c.b;
}
static __device__ __forceinline__ float bflo(uint u) {
  return __uint_as_float(u << 16);
}
static __device__ __forceinline__ float bfhi(uint u) {
  return __uint_as_float(u & 0xFFFF0000u);
}

// ---------------------------------------------------------------------------
// K1: hist (degree + intra-segment position) + fused W_att transpose/scale.
// Wt[f*256 + g*4 + h] = Watt[g*256 + h*64 + f] * SCALE_FOLD
// => q[i][f][h] = sum_g x_i[g] * Watt[g][h*64+f]*SF = SF*(W_att_h @ x_i)[...]
//    and score = sum_f x_src[f] * q_dst[f][h]  (exactly reference's einsum)
// ---------------------------------------------------------------------------
__global__ __launch_bounds__(256) void hist_kernel(
    const int* __restrict__ dst, int* __restrict__ deg, int* __restrict__ epos,
    const float* __restrict__ Watt, float* __restrict__ Wt) {
  int e = blockIdx.x * 256 + threadIdx.x;
  if (e < 16384) {
    int h = e & 3;
    int g = (e >> 2) & 63;
    int f = e >> 8;
    Wt[e] = Watt[g * 256 + h * 64 + f] * SCALE_FOLD;
  }
  if (e < N_EDGES) epos[e] = atomicAdd(&deg[dst[e]], 1);
}

// ---------------------------------------------------------------------------
// K2: per-block sums of x16-padded degrees
// ---------------------------------------------------------------------------
__global__ __launch_bounds__(256) void scan_partials_kernel(
    const int* __restrict__ deg, int* __restrict__ blocksums) {
  __shared__ int red[256];
  const int t = threadIdx.x;
  const int base = blockIdx.x * 1024 + t * 4;
  int s = 0;
  if (base + 3 < N_NODES) {
    int4 d = *(const int4*)(deg + base);
    s = ((d.x + 15) & ~15) + ((d.y + 15) & ~15) + ((d.z + 15) & ~15) +
        ((d.w + 15) & ~15);
  } else {
#pragma unroll
    for (int j = 0; j < 4; ++j)
      if (base + j < N_NODES) s += (deg[base + j] + 15) & ~15;
  }
  red[t] = s;
  __syncthreads();
  for (int d = 128; d > 0; d >>= 1) {
    if (t < d) red[t] += red[t + d];
    __syncthreads();
  }
  if (t == 0) blocksums[blockIdx.x] = red[0];
}

// ---------------------------------------------------------------------------
// K3: final scan + offs + pad-slot fill (src=0, w=0)
// ---------------------------------------------------------------------------
__global__ __launch_bounds__(256) void scan_final_kernel(
    const int* __restrict__ deg, const int* __restrict__ blocksums,
    int* __restrict__ offs, int* __restrict__ csr_src,
    float* __restrict__ csr_w) {
  __shared__ int tsum[256];
  __shared__ int bof_s;
  const int t = threadIdx.x;
  if (t < 64) {
    int v = (t < SCAN_BLOCKS) ? blocksums[t] : 0;
    int inc = v;
#pragma unroll
    for (int d = 1; d < 64; d <<= 1) {
      int u = __shfl_up(inc, d);
      if (t >= d) inc += u;
    }
    if (t == (int)blockIdx.x) bof_s = inc - v;
  }
  const int base = blockIdx.x * 1024 + t * 4;
  int r0 = 0, r1 = 0, r2 = 0, r3 = 0;
  if (base + 3 < N_NODES) {
    int4 d = *(const int4*)(deg + base);
    r0 = d.x; r1 = d.y; r2 = d.z; r3 = d.w;
  } else {
    if (base + 0 < N_NODES) r0 = deg[base + 0];
    if (base + 1 < N_NODES) r1 = deg[base + 1];
    if (base + 2 < N_NODES) r2 = deg[base + 2];
    if (base + 3 < N_NODES) r3 = deg[base + 3];
  }
  const int d0 = (r0 + 15) & ~15, d1 = (r1 + 15) & ~15;
  const int d2 = (r2 + 15) & ~15, d3 = (r3 + 15) & ~15;
  const int s = d0 + d1 + d2 + d3;
  tsum[t] = s;
  __syncthreads();
  int inc2 = s;
  for (int d = 1; d < 256; d <<= 1) {
    int u = (t >= d) ? tsum[t - d] : 0;
    __syncthreads();
    inc2 += u;
    tsum[t] = inc2;
    __syncthreads();
  }
  int o = bof_s + inc2 - s;
  if (base + 0 <= N_NODES) offs[base + 0] = o;
  for (int j = r0; j < d0; ++j) { csr_src[o + j] = 0; csr_w[o + j] = 0.f; }
  o += d0;
  if (base + 1 <= N_NODES) offs[base + 1] = o;
  for (int j = r1; j < d1; ++j) { csr_src[o + j] = 0; csr_w[o + j] = 0.f; }
  o += d1;
  if (base + 2 <= N_NODES) offs[base + 2] = o;
  for (int j = r2; j < d2; ++j) { csr_src[o + j] = 0; csr_w[o + j] = 0.f; }
  o += d2;
  if (base + 3 <= N_NODES) offs[base + 3] = o;
  for (int j = r3; j < d3; ++j) { csr_src[o + j] = 0; csr_w[o + j] = 0.f; }
}

// ---------------------------------------------------------------------------
// K4: scatter edges into padded-CSR order (no atomics)
// ---------------------------------------------------------------------------
__global__ __launch_bounds__(256) void scatter_kernel(
    const int* __restrict__ src, const int* __restrict__ dst,
    const float* __restrict__ ew, const int* __restrict__ offs,
    const int* __restrict__ epos, int* __restrict__ csr_src,
    float* __restrict__ csr_w) {
  int e = blockIdx.x * 256 + threadIdx.x;
  if (e >= N_EDGES) return;
  int idx = offs[dst[e]] + epos[e];
  csr_src[idx] = src[e];
  csr_w[idx] = ew[e];
}

// ---------------------------------------------------------------------------
// K5: q = x @ Wt, packed bf16 hi/lo -> q_packed[node][64 f][4 h] u32.
// Also emits xhi[N][64] bf16 (round-to-nearest of x).
// ---------------------------------------------------------------------------
__global__ __launch_bounds__(256) void qgemm_kernel(
    const float* __restrict__ x, const float* __restrict__ Wt,
    uint4* __restrict__ q_packed, ushort* __restrict__ xhi) {
  __shared__ float xlds[GEMM_ROWS * 64];
  const int tid = threadIdx.x;
  const int blk = blockIdx.x;
#pragma unroll
  for (int p = 0; p < 8; ++p) {
    int idx = p * 256 + tid;
    int gidx = blk * (GEMM_ROWS * 64) + idx;
    xlds[idx] = (gidx < N_NODES * 64) ? x[gidx] : 0.f;
  }
  __syncthreads();
  // emit bf16 hi of x (8 features per thread)
  {
    int row = tid >> 3;
    int c0 = (tid & 7) * 8;
    int grow = blk * GEMM_ROWS + row;
    if (grow < N_NODES) {
      uint hu[4];
#pragma unroll
      for (int d2 = 0; d2 < 4; ++d2) {
        float v0 = xlds[row * 64 + c0 + 2 * d2];
        float v1 = xlds[row * 64 + c0 + 2 * d2 + 1];
        hu[d2] = (uint)bfrn(v0) | ((uint)bfrn(v1) << 16);
      }
      *(uint4*)(xhi + (size_t)grow * 64 + c0) =
          make_uint4(hu[0], hu[1], hu[2], hu[3]);
    }
  }
  const int c4 = tid & 63;
  const int rg = (tid >> 6) * 8;
  const float4* Wv = (const float4*)Wt;
  float4 acc[8] = {};
  for (int k = 0; k < 64; ++k) {
    float4 w4 = Wv[(size_t)k * 64 + c4];
#pragma unroll
    for (int r = 0; r < 8; ++r) {
      float a = xlds[(rg + r) * 64 + k];
      acc[r].x += a * w4.x; acc[r].y += a * w4.y;
      acc[r].z += a * w4.z; acc[r].w += a * w4.w;
    }
  }
#pragma unroll
  for (int r = 0; r < 8; ++r) {
    int row = blk * GEMM_ROWS + rg + r;
    if (row < N_NODES) {
      uint4 pk;
      pk.x = packbf(acc[r].x); pk.y = packbf(acc[r].y);
      pk.z = packbf(acc[r].z); pk.w = packbf(acc[r].w);
      q_packed[(size_t)row * 64 + c4] = pk;  // u32[row*256 + f*4 + h]
    }
  }
}

// ---------------------------------------------------------------------------
// K6: aggregation. One wave/node, 16-edge tiles. NO asm, NO LDS.
// Scores: S^T = Q^T X^T via builtin mfma_f32_16x16x32_bf16:
//   A-frag lane(l15,lg) elem i = q[f][head l15&3] ; B-frag elem i = x_j[f]
//   with the SAME feature map f = 8lg+i (m0) / 32+8lg+i (m1) for A and B
//   -> contraction is correct for ANY hw k-permutation (layout-immune).
// D (m89-verified layout): lane(l15,lg) = S[edge=l15][head=4lg+reg];
//   lanes 0..15 hold the 4 real heads; broadcast p to the wave by
//   ph = __shfl(p_reg, l15) (source lane l15 owns edge l15).
// PV on VALU: acc[4 heads][16 feats-of-lg] += ph*x; recursive-halving
// shuffle reduce (statically indexed) -> 4 values/lane -> bf16 agg write.
// ---------------------------------------------------------------------------
__global__ __launch_bounds__(256) void aggregate_kernel(
    const uint* __restrict__ qp, const uint4* __restrict__ xhi4,
    const int* __restrict__ offs, const int* __restrict__ csr_src,
    const float* __restrict__ csr_w, ushort* __restrict__ agg) {
  const int wave = threadIdx.x >> 6;
  const int node = blockIdx.x * 4 + wave;  // grid exact: 50000 = 4*12500
  const int lane = threadIdx.x & 63;
  const int l15 = lane & 15;
  const int lg = lane >> 4;
  const int hq = l15 & 3;  // head supplied to Q rows (rows 4..15 = dups)

  // ---- Q^T fragments (hi/lo bf16), per node ----
  const uint* qbase = qp + (size_t)node * 256 + hq;
  uint qh0[4], ql0[4], qh1[4], ql1[4];
#pragma unroll
  for (int d = 0; d < 4; ++d) {
    uint a0 = qbase[(8 * lg + 2 * d) * 4];
    uint b0 = qbase[(8 * lg + 2 * d + 1) * 4];
    qh0[d] = (a0 & 0xFFFFu) | (b0 << 16);
    ql0[d] = (a0 >> 16) | (b0 & 0xFFFF0000u);
    uint a1 = qbase[(32 + 8 * lg + 2 * d) * 4];
    uint b1 = qbase[(32 + 8 * lg + 2 * d + 1) * 4];
    qh1[d] = (a1 & 0xFFFFu) | (b1 << 16);
    ql1[d] = (a1 >> 16) | (b1 & 0xFFFF0000u);
  }
  const bf16x8_t Qh0 = as_bf16x8w(qh0[0], qh0[1], qh0[2], qh0[3]);
  const bf16x8_t Qh1 = as_bf16x8w(qh1[0], qh1[1], qh1[2], qh1[3]);
  const bf16x8_t Ql0 = as_bf16x8w(ql0[0], ql0[1], ql0[2], ql0[3]);
  const bf16x8_t Ql1 = as_bf16x8w(ql1[0], ql1[1], ql1[2], ql1[3]);

  const int s0 = offs[node];
  const int s1 = offs[node + 1];

  float a4[4][16];  // [head][feature-of-lg] — statically indexed only
#pragma unroll
  for (int h = 0; h < 4; ++h)
#pragma unroll
    for (int i = 0; i < 16; ++i) a4[h][i] = 0.f;
  float Lp0 = 0.f, Lp1 = 0.f, Lp2 = 0.f, Lp3 = 0.f;

  for (int k0 = s0; k0 < s1; k0 += 16) {
    const int j = csr_src[k0 + l15];
    const float w = csr_w[k0 + l15];
    const uint4 ah0 = xhi4[(size_t)j * 8 + lg];      // feats 8lg..8lg+7
    const uint4 ah1 = xhi4[(size_t)j * 8 + 4 + lg];  // feats 32+8lg..+7
    f32x4_t S = {0.f, 0.f, 0.f, 0.f};
    S = __builtin_amdgcn_mfma_f32_16x16x32_bf16(Qh0, as_bf16x8(ah0), S, 0, 0, 0);
    S = __builtin_amdgcn_mfma_f32_16x16x32_bf16(Qh1, as_bf16x8(ah1), S, 0, 0, 0);
    S = __builtin_amdgcn_mfma_f32_16x16x32_bf16(Ql0, as_bf16x8(ah0), S, 0, 0, 0);
    S = __builtin_amdgcn_mfma_f32_16x16x32_bf16(Ql1, as_bf16x8(ah1), S, 0, 0, 0);
    // p = exp2(leaky(s)) * w  (valid on lanes 0..15: heads 0..3, edge=l15)
    float p0 = exp2f(fmaxf(S[0], 0.2f * S[0])) * w;
    float p1 = exp2f(fmaxf(S[1], 0.2f * S[1])) * w;
    float p2 = exp2f(fmaxf(S[2], 0.2f * S[2])) * w;
    float p3 = exp2f(fmaxf(S[3], 0.2f * S[3])) * w;
    // broadcast: every lane fetches its own edge's p from lane l15
    float ph0 = __shfl(p0, l15);
    float ph1 = __shfl(p1, l15);
    float ph2 = __shfl(p2, l15);
    float ph3 = __shfl(p3, l15);
    Lp0 += ph0; Lp1 += ph1; Lp2 += ph2; Lp3 += ph3;
    // PV: unpack this lane's x chunk and accumulate
    float xf[16];
    xf[0] = bflo(ah0.x);  xf[1] = bfhi(ah0.x);
    xf[2] = bflo(ah0.y);  xf[3] = bfhi(ah0.y);
    xf[4] = bflo(ah0.z);  xf[5] = bfhi(ah0.z);
    xf[6] = bflo(ah0.w);  xf[7] = bfhi(ah0.w);
    xf[8] = bflo(ah1.x);  xf[9] = bfhi(ah1.x);
    xf[10] = bflo(ah1.y); xf[11] = bfhi(ah1.y);
    xf[12] = bflo(ah1.z); xf[13] = bfhi(ah1.z);
    xf[14] = bflo(ah1.w); xf[15] = bfhi(ah1.w);
#pragma unroll
    for (int i = 0; i < 16; ++i) {
      a4[0][i] += ph0 * xf[i];
      a4[1][i] += ph1 * xf[i];
      a4[2][i] += ph2 * xf[i];
      a4[3][i] += ph3 * xf[i];
    }
  }

  // ---- denominators (identical across lg groups; reduce over l15) ----
#pragma unroll
  for (int m = 1; m <= 8; m <<= 1) {
    Lp0 += __shfl_xor(Lp0, m);
    Lp1 += __shfl_xor(Lp1, m);
    Lp2 += __shfl_xor(Lp2, m);
    Lp3 += __shfl_xor(Lp3, m);
  }
  const float inv0 = 1.f / (Lp0 + 1e-16f);
  const float inv1 = 1.f / (Lp1 + 1e-16f);
  const float inv2 = 1.f / (Lp2 + 1e-16f);
  const float inv3 = 1.f / (Lp3 + 1e-16f);

  // ---- recursive-halving reduce over the 16 edge-lanes (all static) ----
  const bool bit3 = (l15 & 8) != 0, bit2 = (l15 & 4) != 0;
  const bool bit1 = (l15 & 2) != 0, bit0 = (l15 & 1) != 0;
  float b0[16], b1[16];
#pragma unroll
  for (int i = 0; i < 16; ++i) {
    float l0 = a4[0][i] + __shfl_xor(a4[0][i], 8);
    float h0 = a4[2][i] + __shfl_xor(a4[2][i], 8);
    b0[i] = bit3 ? h0 : l0;  // head low-pair vs high-pair
    float l1 = a4[1][i] + __shfl_xor(a4[1][i], 8);
    float h1 = a4[3][i] + __shfl_xor(a4[3][i], 8);
    b1[i] = bit3 ? h1 : l1;
  }
  float c[16];
#pragma unroll
  for (int i = 0; i < 16; ++i) {
    float lo = b0[i] + __shfl_xor(b0[i], 4);
    float hi = b1[i] + __shfl_xor(b1[i], 4);
    c[i] = bit2 ? hi : lo;  // head = bit3*2 + bit2 = l15>>2
  }
  float dd[8];
#pragma unroll
  for (int i = 0; i < 8; ++i) {
    float lo = c[i] + __shfl_xor(c[i], 2);
    float hi = c[8 + i] + __shfl_xor(c[8 + i], 2);
    dd[i] = bit1 ? hi : lo;  // feature 8-block = bit1
  }
  float e4[4];
#pragma unroll
  for (int i = 0; i < 4; ++i) {
    float lo = dd[i] + __shfl_xor(dd[i], 1);
    float hi = dd[4 + i] + __shfl_xor(dd[4 + i], 1);
    e4[i] = bit0 ? hi : lo;  // feature 4-block = bit0
  }
  const int h = l15 >> 2;
  const float invh = (h == 0) ? inv0 : (h == 1) ? inv1 : (h == 2) ? inv2 : inv3;
  const int i0 = (bit1 ? 8 : 0) + (bit0 ? 4 : 0);
  const int fbase = (i0 < 8) ? (8 * lg + i0) : (32 + 8 * lg + (i0 - 8));
  uint w0 = (uint)bfrn(e4[0] * invh) | ((uint)bfrn(e4[1] * invh) << 16);
  uint w1 = (uint)bfrn(e4[2] * invh) | ((uint)bfrn(e4[3] * invh) << 16);
  *(uint2*)(agg + (size_t)node * 256 + h * 64 + fbase) = make_uint2(w0, w1);
}

// ---------------------------------------------------------------------------
// K7: out[n, :] = agg(bf16)[n, block-diag] @ Wlin + bias. 32 nodes/block.
// ---------------------------------------------------------------------------
__global__ __launch_bounds__(256) void out_gemm_kernel(
    const ushort* __restrict__ agg, const float* __restrict__ Wlin,
    const float* __restrict__ bias, float* __restrict__ out) {
  __shared__ float4 atile[AGG_NODES][4][17];
  const int tid = threadIdx.x;
  const int node0 = blockIdx.x * AGG_NODES;
  const uint2* av = (const uint2*)agg;
#pragma unroll
  for (int p = 0; p < 8; ++p) {
    int idx = p * 256 + tid;
    int row = idx >> 6;
    int cc = idx & 63;
    if (node0 + row < N_NODES) {
      uint2 u = av[(size_t)(node0 + row) * 64 + cc];
      float4 f;
      f.x = bflo(u.x); f.y = bfhi(u.x);
      f.z = bflo(u.y); f.w = bfhi(u.y);
      atile[row][cc >> 4][cc & 15] = f;
    }
  }
  __syncthreads();
  const int c4 = tid & 63;
  const int ns = tid >> 6;
  const int hh = c4 >> 4;
  const float4* Wv = (const float4*)Wlin;
  float4 acc[8] = {};
  for (int g4 = 0; g4 < 16; ++g4) {
    float4 w0 = Wv[(size_t)(g4 * 4 + 0) * 64 + c4];
    float4 w1 = Wv[(size_t)(g4 * 4 + 1) * 64 + c4];
    float4 w2 = Wv[(size_t)(g4 * 4 + 2) * 64 + c4];
    float4 w3 = Wv[(size_t)(g4 * 4 + 3) * 64 + c4];
#pragma unroll
    for (int n = 0; n < 8; ++n) {
      float4 a = atile[ns * 8 + n][hh][g4];
      acc[n].x += a.x * w0.x + a.y * w1.x + a.z * w2.x + a.w * w3.x;
      acc[n].y += a.x * w0.y + a.y * w1.y + a.z * w2.y + a.w * w3.y;
      acc[n].z += a.x * w0.z + a.y * w1.z + a.z * w2.z + a.w * w3.z;
      acc[n].w += a.x * w0.w + a.y * w1.w + a.z * w2.w + a.w * w3.w;
    }
  }
  float4 bv = ((const float4*)bias)[c4];
#pragma unroll
  for (int n = 0; n < 8; ++n) {
    int node = node0 + ns * 8 + n;
    if (node < N_NODES) {
      float4 o;
      o.x = acc[n].x + bv.x; o.y = acc[n].y + bv.y;
      o.z = acc[n].z + bv.z; o.w = acc[n].w + bv.w;
      ((float4*)out)[(size_t)node * 64 + c4] = o;
    }
  }
}

// ---------------------------------------------------------------------------
extern "C" void kernel_launch(void* const* d_in, const int* in_sizes, int n_in,
                              void* d_out, int out_size, void* d_ws,
                              size_t ws_size, hipStream_t stream) {
  (void)in_sizes; (void)n_in; (void)out_size; (void)ws_size;
  const float* x    = (const float*)d_in[0];
  const int*   ei   = (const int*)d_in[1];
  const float* ew   = (const float*)d_in[2];
  const float* Wlin = (const float*)d_in[3];
  const float* Watt = (const float*)d_in[4];
  const float* bias = (const float*)d_in[5];
  float* out = (float*)d_out;

  const int* srcv = ei;
  const int* dstv = ei + N_EDGES;

  char* ws = (char*)d_ws;
  size_t off = 0;
  auto alloc = [&](size_t bytes) {
    void* p = ws + off;
    off += (bytes + 255) & ~(size_t)255;
    return p;
  };
  // total distinct footprint ~96 MB (kept well under R5's known-good 115 MB)
  uint*   q_packed = (uint*)alloc((size_t)N_NODES * 256 * 4);   // 51.2 MB
  ushort* agg      = (ushort*)alloc((size_t)N_NODES * 256 * 2); // 25.6 MB
  ushort* xhi      = (ushort*)alloc((size_t)N_NODES * 64 * 2);  // 6.4 MB
  int*    offs     = (int*)alloc((size_t)(N_NODES + 1) * 4);
  int*    csr_src  = (int*)alloc((size_t)PAD_EDGES * 4);        // 6.2 MB
  float*  csr_w    = (float*)alloc((size_t)PAD_EDGES * 4);      // 6.2 MB
  int*    blocksums= (int*)alloc((size_t)SCAN_BLOCKS * 4);
  // aliases inside agg (all dead before aggregate_kernel writes agg):
  char* aggc = (char*)agg;
  int*   deg  = (int*)aggc;                         // 200 KB (dead after scan)
  int*   epos = (int*)(aggc + 256 * 1024);          // 3.2 MB (dead after scatter)
  float* Wt   = (float*)(aggc + 4 * 1024 * 1024);   // 64 KB  (dead after qgemm)

  hipMemsetAsync(deg, 0, (size_t)N_NODES * 4, stream);

  hist_kernel<<<(N_EDGES + 255) / 256, 256, 0, stream>>>(dstv, deg, epos,
                                                         Watt, Wt);
  scan_partials_kernel<<<SCAN_BLOCKS, 256, 0, stream>>>(deg, blocksums);
  scan_final_kernel<<<SCAN_BLOCKS, 256, 0, stream>>>(deg, blocksums, offs,
                                                     csr_src, csr_w);
  scatter_kernel<<<(N_EDGES + 255) / 256, 256, 0, stream>>>(
      srcv, dstv, ew, offs, epos, csr_src, csr_w);
  qgemm_kernel<<<(N_NODES + GEMM_ROWS - 1) / GEMM_ROWS, 256, 0, stream>>>(
      x, Wt, (uint4*)q_packed, xhi);
  aggregate_kernel<<<N_NODES / 4, 256, 0, stream>>>(
      q_packed, (const uint4*)xhi, offs, csr_src, csr_w, agg);
  out_gemm_kernel<<<(N_NODES + AGG_NODES - 1) / AGG_NODES, 256, 0, stream>>>(
      agg, Wlin, bias, out);
}

// Round 8
// 175.995 us; speedup vs baseline: 1.2557x; 1.2557x over previous
//
#include <hip/hip_runtime.h>
#include <hip/hip_bf16.h>
#include <math.h>

#define N_NODES 50000
#define N_EDGES 800000
#define GEMM_ROWS 32
#define AGG_NODES 32
#define PAD_EDGES (N_EDGES + N_NODES * 15)  // segments padded to x16
// 0.125 (1/sqrt(64)) * log2(e): folded into Wt -> exp2 in the hot loop.
#define SCALE_FOLD 0.18033688011112042f
#define XT_STRIDE 68  // floats per LDS x-row (64 + 4 pad) -> conflict-light

typedef __attribute__((ext_vector_type(8))) short bf16x8_t;
typedef __attribute__((ext_vector_type(4))) float f32x4_t;

static __device__ __forceinline__ ushort bfrn(float v) {
  __hip_bfloat16 b = __float2bfloat16(v);  // round-to-nearest-even
  return __builtin_bit_cast(ushort, b);
}
static __device__ __forceinline__ uint packbf(float v) {  // hi | lo<<16
  ushort h = bfrn(v);
  float r = v - __uint_as_float((uint)h << 16);
  return (uint)h | ((uint)bfrn(r) << 16);
}
static __device__ __forceinline__ bf16x8_t as_bf16x8(uint4 u) {
  union { uint4 a; bf16x8_t b; } c; c.a = u; return c.b;
}
static __device__ __forceinline__ bf16x8_t as_bf16x8w(uint w0, uint w1,
                                                     uint w2, uint w3) {
  union { uint4 a; bf16x8_t b; } c; c.a = make_uint4(w0, w1, w2, w3); return c.b;
}
static __device__ __forceinline__ float bflo(uint u) {
  return __uint_as_float(u << 16);
}
static __device__ __forceinline__ float bfhi(uint u) {
  return __uint_as_float(u & 0xFFFF0000u);
}

// ---------------------------------------------------------------------------
// K1: hist (degree + intra-segment position) + fused W_att transpose/scale.
// Wt[f*256 + g*4 + h] = Watt[g*256 + h*64 + f] * SCALE_FOLD
// ---------------------------------------------------------------------------
__global__ __launch_bounds__(256) void hist_kernel(
    const int* __restrict__ dst, int* __restrict__ deg, int* __restrict__ epos,
    const float* __restrict__ Watt, float* __restrict__ Wt) {
  int e = blockIdx.x * 256 + threadIdx.x;
  if (e < 16384) {
    int h = e & 3;
    int g = (e >> 2) & 63;
    int f = e >> 8;
    Wt[e] = Watt[g * 256 + h * 64 + f] * SCALE_FOLD;
  }
  if (e < N_EDGES) epos[e] = atomicAdd(&deg[dst[e]], 1);
}

// ---------------------------------------------------------------------------
// K2: per-node base via wave-aggregated atomic on a global cursor.
// Segment bases are unordered (any disjoint layout is valid); per-node
// summation order is fixed by epos -> deterministic output.
// Also fills each segment's pad slots with {src=0, w=0}.
// ---------------------------------------------------------------------------
__global__ __launch_bounds__(256) void base_kernel(
    const int* __restrict__ deg, int* __restrict__ cursor,
    int2* __restrict__ offs2, int2* __restrict__ csr2) {
  const int i = blockIdx.x * 256 + threadIdx.x;
  const int lane = threadIdx.x & 63;
  const int d = (i < N_NODES) ? deg[i] : 0;
  const int nt = (d + 15) >> 4;
  const int pd = nt << 4;
  int incl = pd;  // wave inclusive scan
#pragma unroll
  for (int m = 1; m < 64; m <<= 1) {
    int u = __shfl_up(incl, m);
    if (lane >= m) incl += u;
  }
  int wbase = 0;
  if (lane == 63) wbase = atomicAdd(cursor, incl);
  wbase = __shfl(wbase, 63);
  const int base = wbase + incl - pd;
  if (i < N_NODES) {
    offs2[i] = make_int2(base, nt);
    for (int j = d; j < pd; ++j) csr2[base + j] = make_int2(0, 0);
  }
}

// ---------------------------------------------------------------------------
// K3: scatter edges into padded-CSR order (no atomics; single 8B write)
// ---------------------------------------------------------------------------
__global__ __launch_bounds__(256) void scatter_kernel(
    const int* __restrict__ src, const int* __restrict__ dst,
    const float* __restrict__ ew, const int2* __restrict__ offs2,
    const int* __restrict__ epos, int2* __restrict__ csr2) {
  int e = blockIdx.x * 256 + threadIdx.x;
  if (e >= N_EDGES) return;
  int idx = offs2[dst[e]].x + epos[e];
  csr2[idx] = make_int2(src[e], __float_as_int(ew[e]));
}

// ---------------------------------------------------------------------------
// K4: q = x @ Wt, packed bf16 hi/lo -> q_packed[node][64 f][4 h] u32.
// Also emits xhi[N][64] bf16.
// ---------------------------------------------------------------------------
__global__ __launch_bounds__(256) void qgemm_kernel(
    const float* __restrict__ x, const float* __restrict__ Wt,
    uint4* __restrict__ q_packed, ushort* __restrict__ xhi) {
  __shared__ float xlds[GEMM_ROWS * 64];
  const int tid = threadIdx.x;
  const int blk = blockIdx.x;
#pragma unroll
  for (int p = 0; p < 8; ++p) {
    int idx = p * 256 + tid;
    int gidx = blk * (GEMM_ROWS * 64) + idx;
    xlds[idx] = (gidx < N_NODES * 64) ? x[gidx] : 0.f;
  }
  __syncthreads();
  {
    int row = tid >> 3;
    int c0 = (tid & 7) * 8;
    int grow = blk * GEMM_ROWS + row;
    if (grow < N_NODES) {
      uint hu[4];
#pragma unroll
      for (int d2 = 0; d2 < 4; ++d2) {
        float v0 = xlds[row * 64 + c0 + 2 * d2];
        float v1 = xlds[row * 64 + c0 + 2 * d2 + 1];
        hu[d2] = (uint)bfrn(v0) | ((uint)bfrn(v1) << 16);
      }
      *(uint4*)(xhi + (size_t)grow * 64 + c0) =
          make_uint4(hu[0], hu[1], hu[2], hu[3]);
    }
  }
  const int c4 = tid & 63;
  const int rg = (tid >> 6) * 8;
  const float4* Wv = (const float4*)Wt;
  float4 acc[8] = {};
  for (int k = 0; k < 64; ++k) {
    float4 w4 = Wv[(size_t)k * 64 + c4];
#pragma unroll
    for (int r = 0; r < 8; ++r) {
      float a = xlds[(rg + r) * 64 + k];
      acc[r].x += a * w4.x; acc[r].y += a * w4.y;
      acc[r].z += a * w4.z; acc[r].w += a * w4.w;
    }
  }
#pragma unroll
  for (int r = 0; r < 8; ++r) {
    int row = blk * GEMM_ROWS + rg + r;
    if (row < N_NODES) {
      uint4 pk;
      pk.x = packbf(acc[r].x); pk.y = packbf(acc[r].y);
      pk.z = packbf(acc[r].z); pk.w = packbf(acc[r].w);
      q_packed[(size_t)row * 64 + c4] = pk;  // u32[row*256 + f*4 + h]
    }
  }
}

// ---------------------------------------------------------------------------
// K5: aggregation. One wave/node, 16-edge tiles. MFMA scores (as R7,
// verified), LDS-tile PV with per-lane output ownership:
//   lane (l15,lg) owns (head=lg, feats=l15*4..+3)  -> epilogue has NO
//   cross-lane ops; denominator accumulates from the same p reads.
// Wave-lockstep LDS use (per-wave regions, no barriers).
// ---------------------------------------------------------------------------
__global__ __launch_bounds__(256) void aggregate_kernel(
    const uint4* __restrict__ qp4, const uint4* __restrict__ xhi4,
    const int2* __restrict__ offs2, const int2* __restrict__ csr2,
    ushort* __restrict__ agg) {
  __shared__ uint qlds[4][256];                                   // 4 KB
  __shared__ __attribute__((aligned(16))) float xt[4][16][XT_STRIDE];
  __shared__ __attribute__((aligned(16))) float plds[4][16][4];   // 1 KB
  const int wave = threadIdx.x >> 6;
  const int node = blockIdx.x * 4 + wave;  // grid exact: 50000 = 4*12500
  const int lane = threadIdx.x & 63;
  const int l15 = lane & 15;
  const int lg = lane >> 4;
  const int hq = l15 & 3;

  // stage this node's q row (1KB) coalesced into LDS
  *(uint4*)&qlds[wave][lane * 4] = qp4[(size_t)node * 64 + lane];
  const int2 o2 = offs2[node];

  // build Q^T fragments (hi/lo bf16) from LDS
  uint qh0[4], ql0[4], qh1[4], ql1[4];
#pragma unroll
  for (int d = 0; d < 4; ++d) {
    uint a0 = qlds[wave][(8 * lg + 2 * d) * 4 + hq];
    uint b0 = qlds[wave][(8 * lg + 2 * d + 1) * 4 + hq];
    qh0[d] = (a0 & 0xFFFFu) | (b0 << 16);
    ql0[d] = (a0 >> 16) | (b0 & 0xFFFF0000u);
    uint a1 = qlds[wave][(32 + 8 * lg + 2 * d) * 4 + hq];
    uint b1 = qlds[wave][(32 + 8 * lg + 2 * d + 1) * 4 + hq];
    qh1[d] = (a1 & 0xFFFFu) | (b1 << 16);
    ql1[d] = (a1 >> 16) | (b1 & 0xFFFF0000u);
  }
  const bf16x8_t Qh0 = as_bf16x8w(qh0[0], qh0[1], qh0[2], qh0[3]);
  const bf16x8_t Qh1 = as_bf16x8w(qh1[0], qh1[1], qh1[2], qh1[3]);
  const bf16x8_t Ql0 = as_bf16x8w(ql0[0], ql0[1], ql0[2], ql0[3]);
  const bf16x8_t Ql1 = as_bf16x8w(ql1[0], ql1[1], ql1[2], ql1[3]);

  const int s0 = o2.x;
  const int ntiles = o2.y;

  f32x4_t acc = {0.f, 0.f, 0.f, 0.f};
  float Lp = 0.f;

  for (int t = 0; t < ntiles; ++t) {
    const int k0 = s0 + t * 16;
    const int2 e2 = csr2[k0 + l15];
    const int j = e2.x;
    const float w = __int_as_float(e2.y);
    const uint4 ah0 = xhi4[(size_t)j * 8 + lg];      // feats 8lg..8lg+7
    const uint4 ah1 = xhi4[(size_t)j * 8 + 4 + lg];  // feats 32+8lg..+7
    // scores: S[edge=l15][head=reg] on every lane (rows 4..15 dup heads)
    f32x4_t S = {0.f, 0.f, 0.f, 0.f};
    S = __builtin_amdgcn_mfma_f32_16x16x32_bf16(Qh0, as_bf16x8(ah0), S, 0, 0, 0);
    S = __builtin_amdgcn_mfma_f32_16x16x32_bf16(Qh1, as_bf16x8(ah1), S, 0, 0, 0);
    S = __builtin_amdgcn_mfma_f32_16x16x32_bf16(Ql0, as_bf16x8(ah0), S, 0, 0, 0);
    S = __builtin_amdgcn_mfma_f32_16x16x32_bf16(Ql1, as_bf16x8(ah1), S, 0, 0, 0);
    // stage x (f32) into the wave's LDS tile
    float xf[16];
    xf[0] = bflo(ah0.x);  xf[1] = bfhi(ah0.x);
    xf[2] = bflo(ah0.y);  xf[3] = bfhi(ah0.y);
    xf[4] = bflo(ah0.z);  xf[5] = bfhi(ah0.z);
    xf[6] = bflo(ah0.w);  xf[7] = bfhi(ah0.w);
    xf[8] = bflo(ah1.x);  xf[9] = bfhi(ah1.x);
    xf[10] = bflo(ah1.y); xf[11] = bfhi(ah1.y);
    xf[12] = bflo(ah1.z); xf[13] = bfhi(ah1.z);
    xf[14] = bflo(ah1.w); xf[15] = bfhi(ah1.w);
    *(float4*)&xt[wave][l15][8 * lg + 0] =
        make_float4(xf[0], xf[1], xf[2], xf[3]);
    *(float4*)&xt[wave][l15][8 * lg + 4] =
        make_float4(xf[4], xf[5], xf[6], xf[7]);
    *(float4*)&xt[wave][l15][32 + 8 * lg + 0] =
        make_float4(xf[8], xf[9], xf[10], xf[11]);
    *(float4*)&xt[wave][l15][32 + 8 * lg + 4] =
        make_float4(xf[12], xf[13], xf[14], xf[15]);
    // p = exp2(leaky(s)) * w, written by the lg==0 group (edge l15)
    float p0 = exp2f(fmaxf(S[0], 0.2f * S[0])) * w;
    float p1 = exp2f(fmaxf(S[1], 0.2f * S[1])) * w;
    float p2 = exp2f(fmaxf(S[2], 0.2f * S[2])) * w;
    float p3 = exp2f(fmaxf(S[3], 0.2f * S[3])) * w;
    if (lg == 0) *(float4*)&plds[wave][l15][0] = make_float4(p0, p1, p2, p3);
    // PV: lane owns (head=lg, feats=l15*4..+3); p-read doubles as denom
#pragma unroll
    for (int e = 0; e < 16; ++e) {
      float4 xv = *(const float4*)&xt[wave][e][l15 * 4];
      float pe = plds[wave][e][lg];
      acc[0] += pe * xv.x; acc[1] += pe * xv.y;
      acc[2] += pe * xv.z; acc[3] += pe * xv.w;
      Lp += pe;
    }
  }

  const float inv = 1.f / (Lp + 1e-16f);
  uint w0 = (uint)bfrn(acc[0] * inv) | ((uint)bfrn(acc[1] * inv) << 16);
  uint w1 = (uint)bfrn(acc[2] * inv) | ((uint)bfrn(acc[3] * inv) << 16);
  *(uint2*)(agg + (size_t)node * 256 + lg * 64 + l15 * 4) = make_uint2(w0, w1);
}

// ---------------------------------------------------------------------------
// K6: out[n, :] = agg(bf16)[n, block-diag] @ Wlin + bias. 32 nodes/block.
// ---------------------------------------------------------------------------
__global__ __launch_bounds__(256) void out_gemm_kernel(
    const ushort* __restrict__ agg, const float* __restrict__ Wlin,
    const float* __restrict__ bias, float* __restrict__ out) {
  __shared__ float4 atile[AGG_NODES][4][17];
  const int tid = threadIdx.x;
  const int node0 = blockIdx.x * AGG_NODES;
  const uint2* av = (const uint2*)agg;
#pragma unroll
  for (int p = 0; p < 8; ++p) {
    int idx = p * 256 + tid;
    int row = idx >> 6;
    int cc = idx & 63;
    if (node0 + row < N_NODES) {
      uint2 u = av[(size_t)(node0 + row) * 64 + cc];
      float4 f;
      f.x = bflo(u.x); f.y = bfhi(u.x);
      f.z = bflo(u.y); f.w = bfhi(u.y);
      atile[row][cc >> 4][cc & 15] = f;
    }
  }
  __syncthreads();
  const int c4 = tid & 63;
  const int ns = tid >> 6;
  const int hh = c4 >> 4;
  const float4* Wv = (const float4*)Wlin;
  float4 acc[8] = {};
  for (int g4 = 0; g4 < 16; ++g4) {
    float4 w0 = Wv[(size_t)(g4 * 4 + 0) * 64 + c4];
    float4 w1 = Wv[(size_t)(g4 * 4 + 1) * 64 + c4];
    float4 w2 = Wv[(size_t)(g4 * 4 + 2) * 64 + c4];
    float4 w3 = Wv[(size_t)(g4 * 4 + 3) * 64 + c4];
#pragma unroll
    for (int n = 0; n < 8; ++n) {
      float4 a = atile[ns * 8 + n][hh][g4];
      acc[n].x += a.x * w0.x + a.y * w1.x + a.z * w2.x + a.w * w3.x;
      acc[n].y += a.x * w0.y + a.y * w1.y + a.z * w2.y + a.w * w3.y;
      acc[n].z += a.x * w0.z + a.y * w1.z + a.z * w2.z + a.w * w3.z;
      acc[n].w += a.x * w0.w + a.y * w1.w + a.z * w2.w + a.w * w3.w;
    }
  }
  float4 bv = ((const float4*)bias)[c4];
#pragma unroll
  for (int n = 0; n < 8; ++n) {
    int node = node0 + ns * 8 + n;
    if (node < N_NODES) {
      float4 o;
      o.x = acc[n].x + bv.x; o.y = acc[n].y + bv.y;
      o.z = acc[n].z + bv.z; o.w = acc[n].w + bv.w;
      ((float4*)out)[(size_t)node * 64 + c4] = o;
    }
  }
}

// ---------------------------------------------------------------------------
extern "C" void kernel_launch(void* const* d_in, const int* in_sizes, int n_in,
                              void* d_out, int out_size, void* d_ws,
                              size_t ws_size, hipStream_t stream) {
  (void)in_sizes; (void)n_in; (void)out_size; (void)ws_size;
  const float* x    = (const float*)d_in[0];
  const int*   ei   = (const int*)d_in[1];
  const float* ew   = (const float*)d_in[2];
  const float* Wlin = (const float*)d_in[3];
  const float* Watt = (const float*)d_in[4];
  const float* bias = (const float*)d_in[5];
  float* out = (float*)d_out;

  const int* srcv = ei;
  const int* dstv = ei + N_EDGES;

  char* ws = (char*)d_ws;
  size_t off = 0;
  auto alloc = [&](size_t bytes) {
    void* p = ws + off;
    off += (bytes + 255) & ~(size_t)255;
    return p;
  };
  // distinct footprint ~96 MB
  uint*   q_packed = (uint*)alloc((size_t)N_NODES * 256 * 4);    // 51.2 MB
  ushort* agg      = (ushort*)alloc((size_t)N_NODES * 256 * 2);  // 25.6 MB
  ushort* xhi      = (ushort*)alloc((size_t)N_NODES * 64 * 2);   // 6.4 MB
  int2*   offs2    = (int2*)alloc((size_t)N_NODES * 8);          // 0.4 MB
  int2*   csr2     = (int2*)alloc((size_t)PAD_EDGES * 8);        // 12.4 MB
  // aliases inside agg (all dead before aggregate_kernel writes agg):
  char* aggc = (char*)agg;
  int*   deg    = (int*)aggc;                       // 200 KB (dead after base)
  int*   cursor = (int*)(aggc + N_NODES * 4);       // 4 B    (dead after base)
  int*   epos   = (int*)(aggc + 256 * 1024);        // 3.2 MB (dead after scatter)
  float* Wt     = (float*)(aggc + 4 * 1024 * 1024); // 64 KB  (dead after qgemm)

  hipMemsetAsync(deg, 0, (size_t)(N_NODES + 64) * 4, stream);  // deg + cursor

  hist_kernel<<<(N_EDGES + 255) / 256, 256, 0, stream>>>(dstv, deg, epos,
                                                         Watt, Wt);
  base_kernel<<<(N_NODES + 255) / 256, 256, 0, stream>>>(deg, cursor, offs2,
                                                         csr2);
  scatter_kernel<<<(N_EDGES + 255) / 256, 256, 0, stream>>>(
      srcv, dstv, ew, offs2, epos, csr2);
  qgemm_kernel<<<(N_NODES + GEMM_ROWS - 1) / GEMM_ROWS, 256, 0, stream>>>(
      x, Wt, (uint4*)q_packed, xhi);
  aggregate_kernel<<<N_NODES / 4, 256, 0, stream>>>(
      (const uint4*)q_packed, (const uint4*)xhi, offs2, csr2, agg);
  out_gemm_kernel<<<(N_NODES + AGG_NODES - 1) / AGG_NODES, 256, 0, stream>>>(
      agg, Wlin, bias, out);
}

// Round 11
// 170.913 us; speedup vs baseline: 1.2930x; 1.0297x over previous
//
#include <hip/hip_runtime.h>
#include <hip/hip_bf16.h>
#include <math.h>

#define N_NODES 50000
#define N_EDGES 800000
#define GEMM_ROWS 32
#define AGG_NODES 32
#define PAD_EDGES (N_EDGES + N_NODES * 15)  // segments padded to x16
#define QGEMM_BLOCKS ((N_NODES + GEMM_ROWS - 1) / GEMM_ROWS)  // 1563
#define BASE_BLOCKS ((N_NODES + 255) / 256)                    // 196
// 0.125 (1/sqrt(64)) * log2(e): folded into Wt -> exp2 in the hot loop.
#define SCALE_FOLD 0.18033688011112042f
// u32 per LDS x-row; row pitch must be 16B-multiple for uint4 stores: 36*4=144.
#define XT_STRIDE 36

typedef __attribute__((ext_vector_type(8))) short bf16x8_t;
typedef __attribute__((ext_vector_type(4))) float f32x4_t;

static __device__ __forceinline__ ushort bfrn(float v) {
  __hip_bfloat16 b = __float2bfloat16(v);  // round-to-nearest-even
  return __builtin_bit_cast(ushort, b);
}
static __device__ __forceinline__ bf16x8_t as_bf16x8(uint4 u) {
  union { uint4 a; bf16x8_t b; } c; c.a = u; return c.b;
}
static __device__ __forceinline__ float bflo(uint u) {
  return __uint_as_float(u << 16);
}
static __device__ __forceinline__ float bfhi(uint u) {
  return __uint_as_float(u & 0xFFFF0000u);
}

// ---------------------------------------------------------------------------
// K1: hist (degree + intra-segment position) + fused W_att^T transpose/scale.
// Wt[h*4096 + r*64 + c] = Watt[c*256 + h*64 + r] * SCALE_FOLD
//   (r = contraction row for the q-GEMM, c = output col = Watt's g index)
// => q_t[i][h][c] = sum_r x_i[r] * Watt[c][h*64+r]   (q = Watt_h^T-projected)
//    score[e,h] = sum_c q_t[dst][h][c] * x_src[c] = u[src].x[dst]  (reference)
// R9/R10 BUG was here: contracting Watt's first axis gave u[dst] (direction
// reversed). This is the corrected transpose.
// ---------------------------------------------------------------------------
__global__ __launch_bounds__(256) void hist_kernel(
    const int* __restrict__ dst, int* __restrict__ deg, int* __restrict__ epos,
    const float* __restrict__ Watt, float* __restrict__ Wt) {
  int e = blockIdx.x * 256 + threadIdx.x;
  if (e < 16384) {
    int c = e & 63;
    int r = (e >> 6) & 63;
    int h = e >> 12;
    Wt[e] = Watt[c * 256 + h * 64 + r] * SCALE_FOLD;
  }
  if (e < N_EDGES) epos[e] = atomicAdd(&deg[dst[e]], 1);
}

// ---------------------------------------------------------------------------
// K2 (merged): blocks [0, QGEMM_BLOCKS) : q = x @ Wt -> q_t bf16 [node][h][f],
//              plus xhi[N][64] bf16 emission.
//              blocks [QGEMM_BLOCKS, +BASE_BLOCKS): per-node CSR base via
//              wave-aggregated atomic + pad-slot fill.
// Both depend only on hist output.
// ---------------------------------------------------------------------------
__global__ __launch_bounds__(256) void qgemm_base_kernel(
    const float* __restrict__ x, const float* __restrict__ Wt,
    uint2* __restrict__ q_t2, ushort* __restrict__ xhi,
    const int* __restrict__ deg, int* __restrict__ cursor,
    int2* __restrict__ offs2, int2* __restrict__ csr2) {
  const int tid = threadIdx.x;
  if (blockIdx.x >= QGEMM_BLOCKS) {
    // ---- base part ----
    const int i = (blockIdx.x - QGEMM_BLOCKS) * 256 + tid;
    const int lane = tid & 63;
    const int d = (i < N_NODES) ? deg[i] : 0;
    const int nt = (d + 15) >> 4;
    const int pd = nt << 4;
    int incl = pd;  // wave inclusive scan
#pragma unroll
    for (int m = 1; m < 64; m <<= 1) {
      int u = __shfl_up(incl, m);
      if (lane >= m) incl += u;
    }
    int wbase = 0;
    if (lane == 63) wbase = atomicAdd(cursor, incl);
    wbase = __shfl(wbase, 63);
    const int base = wbase + incl - pd;
    if (i < N_NODES) {
      offs2[i] = make_int2(base, nt);
      for (int j = d; j < pd; ++j) csr2[base + j] = make_int2(0, 0);
    }
    return;
  }
  // ---- qgemm part ----
  __shared__ float xlds[GEMM_ROWS * 64];
  const int blk = blockIdx.x;
#pragma unroll
  for (int p = 0; p < 8; ++p) {
    int idx = p * 256 + tid;
    int gidx = blk * (GEMM_ROWS * 64) + idx;
    xlds[idx] = (gidx < N_NODES * 64) ? x[gidx] : 0.f;
  }
  __syncthreads();
  {
    int row = tid >> 3;
    int c0 = (tid & 7) * 8;
    int grow = blk * GEMM_ROWS + row;
    if (grow < N_NODES) {
      uint hu[4];
#pragma unroll
      for (int d2 = 0; d2 < 4; ++d2) {
        float v0 = xlds[row * 64 + c0 + 2 * d2];
        float v1 = xlds[row * 64 + c0 + 2 * d2 + 1];
        hu[d2] = (uint)bfrn(v0) | ((uint)bfrn(v1) << 16);
      }
      *(uint4*)(xhi + (size_t)grow * 64 + c0) =
          make_uint4(hu[0], hu[1], hu[2], hu[3]);
    }
  }
  const int c4 = tid & 63;        // h = c4>>4, f4 = c4&15 (feats 4f4..4f4+3)
  const int h = c4 >> 4;
  const int f4 = c4 & 15;
  const int rg = (tid >> 6) * 8;
  const float4* Wv = (const float4*)Wt;
  float4 acc[8] = {};
  for (int g = 0; g < 64; ++g) {
    float4 w4 = Wv[(size_t)h * 1024 + g * 16 + f4];
#pragma unroll
    for (int r = 0; r < 8; ++r) {
      float a = xlds[(rg + r) * 64 + g];
      acc[r].x += a * w4.x; acc[r].y += a * w4.y;
      acc[r].z += a * w4.z; acc[r].w += a * w4.w;
    }
  }
#pragma unroll
  for (int r = 0; r < 8; ++r) {
    int row = blk * GEMM_ROWS + rg + r;
    if (row < N_NODES) {
      uint2 pk;
      pk.x = (uint)bfrn(acc[r].x) | ((uint)bfrn(acc[r].y) << 16);
      pk.y = (uint)bfrn(acc[r].z) | ((uint)bfrn(acc[r].w) << 16);
      q_t2[(size_t)row * 64 + c4] = pk;  // ushort[row*256 + h*64 + 4f4..]
    }
  }
}

// ---------------------------------------------------------------------------
// K3: scatter edges into padded-CSR order (no atomics; single 8B write)
// ---------------------------------------------------------------------------
__global__ __launch_bounds__(256) void scatter_kernel(
    const int* __restrict__ src, const int* __restrict__ dst,
    const float* __restrict__ ew, const int2* __restrict__ offs2,
    const int* __restrict__ epos, int2* __restrict__ csr2) {
  int e = blockIdx.x * 256 + threadIdx.x;
  if (e >= N_EDGES) return;
  int idx = offs2[dst[e]].x + epos[e];
  csr2[idx] = make_int2(src[e], __float_as_int(ew[e]));
}

// ---------------------------------------------------------------------------
// K4: aggregation. One wave/node, 16-edge tiles.
// Scores: 2x mfma_f32_16x16x32_bf16 (A = q_t fragment loaded raw from
// global — layout [node][h][f] makes the fragment 2x 16B loads, no VALU).
// A and B use the IDENTICAL (lane,elem)->feature map -> contraction correct
// for any hw k-permutation. D layout (m89-verified): lane(l15,lg) reg R =
// S[edge=l15][head=R].
// PV: x-tile staged raw bf16 (uint4) in LDS; lane owns (head=lg,
// feats=4*l15..+3): 16x {ds_read_b64 + p broadcast + 4 unpack + 4 FMA}.
// Denominator accumulates from the same p reads. Wave-lockstep LDS.
// ---------------------------------------------------------------------------
__global__ __launch_bounds__(256) void aggregate_kernel(
    const uint4* __restrict__ qt4, const uint4* __restrict__ xhi4,
    const int2* __restrict__ offs2, const int2* __restrict__ csr2,
    ushort* __restrict__ agg) {
  __shared__ __attribute__((aligned(16))) uint xt[4][16][XT_STRIDE];  // 9.2 KB
  __shared__ __attribute__((aligned(16))) float plds[4][16][4];       // 1 KB
  const int wave = threadIdx.x >> 6;
  const int node = blockIdx.x * 4 + wave;  // grid exact: 50000 = 4*12500
  const int lane = threadIdx.x & 63;
  const int l15 = lane & 15;
  const int lg = lane >> 4;
  const int hq = l15 & 3;

  // Q fragments: feats 8lg..8lg+7 and 32+8lg..+7 of head hq — raw loads
  const bf16x8_t Qa =
      as_bf16x8(qt4[(size_t)node * 32 + hq * 8 + lg]);
  const bf16x8_t Qb =
      as_bf16x8(qt4[(size_t)node * 32 + hq * 8 + 4 + lg]);
  const int2 o2 = offs2[node];
  const int s0 = o2.x;
  const int ntiles = o2.y;

  f32x4_t acc = {0.f, 0.f, 0.f, 0.f};
  float Lp = 0.f;

  for (int t = 0; t < ntiles; ++t) {
    const int k0 = s0 + t * 16;
    const int2 e2 = csr2[k0 + l15];
    const int j = e2.x;
    const float w = __int_as_float(e2.y);
    const uint4 ah0 = xhi4[(size_t)j * 8 + lg];      // feats 8lg..8lg+7
    const uint4 ah1 = xhi4[(size_t)j * 8 + 4 + lg];  // feats 32+8lg..+7
    // stage raw bf16 x rows: u32 cols 4lg.. and 16+4lg.. (both 16B-aligned)
    *(uint4*)&xt[wave][l15][4 * lg] = ah0;
    *(uint4*)&xt[wave][l15][16 + 4 * lg] = ah1;
    // scores: S[edge=l15][head=reg] on every lane
    f32x4_t S = {0.f, 0.f, 0.f, 0.f};
    S = __builtin_amdgcn_mfma_f32_16x16x32_bf16(Qa, as_bf16x8(ah0), S, 0, 0, 0);
    S = __builtin_amdgcn_mfma_f32_16x16x32_bf16(Qb, as_bf16x8(ah1), S, 0, 0, 0);
    // p = exp2(leaky(s)) * w; edge l15's p written by the lg==0 group
    float p0 = exp2f(fmaxf(S[0], 0.2f * S[0])) * w;
    float p1 = exp2f(fmaxf(S[1], 0.2f * S[1])) * w;
    float p2 = exp2f(fmaxf(S[2], 0.2f * S[2])) * w;
    float p3 = exp2f(fmaxf(S[3], 0.2f * S[3])) * w;
    if (lg == 0) *(float4*)&plds[wave][l15][0] = make_float4(p0, p1, p2, p3);
    // PV: lane owns (head=lg, feats=4*l15..+3) = u32 cols 2*l15, 2*l15+1
#pragma unroll
    for (int e = 0; e < 16; ++e) {
      uint2 xw = *(const uint2*)&xt[wave][e][2 * l15];
      float pe = plds[wave][e][lg];
      acc[0] += pe * bflo(xw.x);
      acc[1] += pe * bfhi(xw.x);
      acc[2] += pe * bflo(xw.y);
      acc[3] += pe * bfhi(xw.y);
      Lp += pe;
    }
  }

  const float inv = 1.f / (Lp + 1e-16f);
  uint w0 = (uint)bfrn(acc[0] * inv) | ((uint)bfrn(acc[1] * inv) << 16);
  uint w1 = (uint)bfrn(acc[2] * inv) | ((uint)bfrn(acc[3] * inv) << 16);
  *(uint2*)(agg + (size_t)node * 256 + lg * 64 + l15 * 4) = make_uint2(w0, w1);
}

// ---------------------------------------------------------------------------
// K5: out[n, :] = agg(bf16)[n, block-diag] @ Wlin + bias. 32 nodes/block.
// ---------------------------------------------------------------------------
__global__ __launch_bounds__(256) void out_gemm_kernel(
    const ushort* __restrict__ agg, const float* __restrict__ Wlin,
    const float* __restrict__ bias, float* __restrict__ out) {
  __shared__ float4 atile[AGG_NODES][4][17];
  const int tid = threadIdx.x;
  const int node0 = blockIdx.x * AGG_NODES;
  const uint2* av = (const uint2*)agg;
#pragma unroll
  for (int p = 0; p < 8; ++p) {
    int idx = p * 256 + tid;
    int row = idx >> 6;
    int cc = idx & 63;
    if (node0 + row < N_NODES) {
      uint2 u = av[(size_t)(node0 + row) * 64 + cc];
      float4 f;
      f.x = bflo(u.x); f.y = bfhi(u.x);
      f.z = bflo(u.y); f.w = bfhi(u.y);
      atile[row][cc >> 4][cc & 15] = f;
    }
  }
  __syncthreads();
  const int c4 = tid & 63;
  const int ns = tid >> 6;
  const int hh = c4 >> 4;
  const float4* Wv = (const float4*)Wlin;
  float4 acc[8] = {};
  for (int g4 = 0; g4 < 16; ++g4) {
    float4 w0 = Wv[(size_t)(g4 * 4 + 0) * 64 + c4];
    float4 w1 = Wv[(size_t)(g4 * 4 + 1) * 64 + c4];
    float4 w2 = Wv[(size_t)(g4 * 4 + 2) * 64 + c4];
    float4 w3 = Wv[(size_t)(g4 * 4 + 3) * 64 + c4];
#pragma unroll
    for (int n = 0; n < 8; ++n) {
      float4 a = atile[ns * 8 + n][hh][g4];
      acc[n].x += a.x * w0.x + a.y * w1.x + a.z * w2.x + a.w * w3.x;
      acc[n].y += a.x * w0.y + a.y * w1.y + a.z * w2.y + a.w * w3.y;
      acc[n].z += a.x * w0.z + a.y * w1.z + a.z * w2.z + a.w * w3.z;
      acc[n].w += a.x * w0.w + a.y * w1.w + a.z * w2.w + a.w * w3.w;
    }
  }
  float4 bv = ((const float4*)bias)[c4];
#pragma unroll
  for (int n = 0; n < 8; ++n) {
    int node = node0 + ns * 8 + n;
    if (node < N_NODES) {
      float4 o;
      o.x = acc[n].x + bv.x; o.y = acc[n].y + bv.y;
      o.z = acc[n].z + bv.z; o.w = acc[n].w + bv.w;
      ((float4*)out)[(size_t)node * 64 + c4] = o;
    }
  }
}

// ---------------------------------------------------------------------------
extern "C" void kernel_launch(void* const* d_in, const int* in_sizes, int n_in,
                              void* d_out, int out_size, void* d_ws,
                              size_t ws_size, hipStream_t stream) {
  (void)in_sizes; (void)n_in; (void)out_size; (void)ws_size;
  const float* x    = (const float*)d_in[0];
  const int*   ei   = (const int*)d_in[1];
  const float* ew   = (const float*)d_in[2];
  const float* Wlin = (const float*)d_in[3];
  const float* Watt = (const float*)d_in[4];
  const float* bias = (const float*)d_in[5];
  float* out = (float*)d_out;

  const int* srcv = ei;
  const int* dstv = ei + N_EDGES;

  char* ws = (char*)d_ws;
  size_t off = 0;
  auto alloc = [&](size_t bytes) {
    void* p = ws + off;
    off += (bytes + 255) & ~(size_t)255;
    return p;
  };
  // distinct footprint ~71 MB
  ushort* q_t   = (ushort*)alloc((size_t)N_NODES * 256 * 2);  // 25.6 MB
  ushort* agg   = (ushort*)alloc((size_t)N_NODES * 256 * 2);  // 25.6 MB
  ushort* xhi   = (ushort*)alloc((size_t)N_NODES * 64 * 2);   // 6.4 MB
  int2*   offs2 = (int2*)alloc((size_t)N_NODES * 8);          // 0.4 MB
  int2*   csr2  = (int2*)alloc((size_t)PAD_EDGES * 8);        // 12.4 MB
  // aliases inside agg (all dead before aggregate_kernel writes agg):
  char* aggc = (char*)agg;
  int*   deg    = (int*)aggc;                       // 200 KB (dead after base)
  int*   cursor = (int*)(aggc + N_NODES * 4);       // 4 B    (dead after base)
  int*   epos   = (int*)(aggc + 256 * 1024);        // 3.2 MB (dead after scatter)
  float* Wt     = (float*)(aggc + 4 * 1024 * 1024); // 64 KB  (dead after qgemm)

  hipMemsetAsync(deg, 0, (size_t)(N_NODES + 64) * 4, stream);  // deg + cursor

  hist_kernel<<<(N_EDGES + 255) / 256, 256, 0, stream>>>(dstv, deg, epos,
                                                         Watt, Wt);
  qgemm_base_kernel<<<QGEMM_BLOCKS + BASE_BLOCKS, 256, 0, stream>>>(
      x, Wt, (uint2*)q_t, xhi, deg, cursor, offs2, csr2);
  scatter_kernel<<<(N_EDGES + 255) / 256, 256, 0, stream>>>(
      srcv, dstv, ew, offs2, epos, csr2);
  aggregate_kernel<<<N_NODES / 4, 256, 0, stream>>>(
      (const uint4*)q_t, (const uint4*)xhi, offs2, csr2, agg);
  out_gemm_kernel<<<(N_NODES + AGG_NODES - 1) / AGG_NODES, 256, 0, stream>>>(
      agg, Wlin, bias, out);
}

// Round 13
// 170.804 us; speedup vs baseline: 1.2938x; 1.0006x over previous
//
#include <hip/hip_runtime.h>
#include <hip/hip_cooperative_groups.h>
#include <hip/hip_bf16.h>
#include <math.h>

namespace cg = cooperative_groups;

#define N_NODES 50000
#define N_EDGES 800000
#define GEMM_ROWS 32
#define AGG_NODES 32
#define PAD_EDGES (N_EDGES + N_NODES * 15)  // segments padded to x16
#define QGEMM_BLOCKS ((N_NODES + GEMM_ROWS - 1) / GEMM_ROWS)  // 1563
#define SCAT_CHUNKS ((N_EDGES + 255) / 256)                    // 3125
#define BASE_BLOCKS ((N_NODES + 255) / 256)                    // 196
#define AGG_VB (N_NODES / 4)                                   // 12500
#define OUT_VB (N_NODES / 16)                                  // 3125 (exact)
#define GRID_WANT 1024
#define NUM_CU 256
// 0.125 (1/sqrt(64)) * log2(e): folded into Wt -> exp2 in the hot loop.
#define SCALE_FOLD 0.18033688011112042f
// u32 per LDS x-row; row pitch must be 16B-multiple for uint4 stores: 36*4=144.
#define XT_STRIDE 36

typedef __attribute__((ext_vector_type(8))) short bf16x8_t;
typedef __attribute__((ext_vector_type(4))) float f32x4_t;

static __device__ __forceinline__ ushort bfrn(float v) {
  __hip_bfloat16 b = __float2bfloat16(v);  // round-to-nearest-even
  return __builtin_bit_cast(ushort, b);
}
static __device__ __forceinline__ bf16x8_t as_bf16x8(uint4 u) {
  union { uint4 a; bf16x8_t b; } c; c.a = u; return c.b;
}
static __device__ __forceinline__ float bflo(uint u) {
  return __uint_as_float(u << 16);
}
static __device__ __forceinline__ float bfhi(uint u) {
  return __uint_as_float(u & 0xFFFF0000u);
}

// ===========================================================================
// Cooperative mega-kernel: 6 phases split by grid.sync().
// All phase loops stride by gridDim.x (any grid >= 256 blocks is correct).
// ===========================================================================
__global__ __launch_bounds__(256) void mega_kernel(
    const float* __restrict__ x, const int* __restrict__ srcv,
    const int* __restrict__ dstv, const float* __restrict__ ew,
    const float* __restrict__ Wlin, const float* __restrict__ bias,
    const float* __restrict__ Watt, float* __restrict__ out,
    ushort* __restrict__ q_t, ushort* __restrict__ xhi,
    ushort* __restrict__ agg, int2* __restrict__ offs2,
    int2* __restrict__ csr2, int* __restrict__ deg,
    int* __restrict__ cursor, int* __restrict__ epos,
    float* __restrict__ Wt) {
  __shared__ __attribute__((aligned(16))) char pool[17408];
  cg::grid_group grid = cg::this_grid();
  const int tid = threadIdx.x;
  const int bid = blockIdx.x;
  const int nblk = gridDim.x;
  const int gtid = bid * 256 + tid;
  const int gthreads = nblk * 256;
  const int lane = tid & 63;
  const int wave = tid >> 6;

  // ---- Phase A: zero deg + cursor ----
  for (int i = gtid; i < N_NODES; i += gthreads) deg[i] = 0;
  if (gtid == 0) cursor[0] = 0;
  __threadfence();
  grid.sync();

  // ---- Phase B: Watt^T transpose/scale + degree histogram ----
  if (gtid < 16384) {
    int c = gtid & 63, r = (gtid >> 6) & 63, h = gtid >> 12;
    Wt[gtid] = Watt[c * 256 + h * 64 + r] * SCALE_FOLD;
  }
  for (int e = gtid; e < N_EDGES; e += gthreads)
    epos[e] = atomicAdd(&deg[dstv[e]], 1);
  __threadfence();
  grid.sync();

  // ---- Phase C: segment bases (wave-aggregated atomic) + pad fill ----
  if (bid < BASE_BLOCKS) {
    const int i = gtid;
    const int d = (i < N_NODES) ? deg[i] : 0;
    const int nt = (d + 15) >> 4;
    const int pd = nt << 4;
    int incl = pd;
#pragma unroll
    for (int m = 1; m < 64; m <<= 1) {
      int u = __shfl_up(incl, m);
      if (lane >= m) incl += u;
    }
    int wbase = 0;
    if (lane == 63) wbase = atomicAdd(cursor, incl);
    wbase = __shfl(wbase, 63);
    const int base = wbase + incl - pd;
    if (i < N_NODES) {
      offs2[i] = make_int2(base, nt);
      for (int j = d; j < pd; ++j) csr2[base + j] = make_int2(0, 0);
    }
  }
  __threadfence();
  grid.sync();

  // ---- Phase D: qgemm tiles (vb < QGEMM_BLOCKS) || scatter chunks ----
  for (int vb = bid; vb < QGEMM_BLOCKS + SCAT_CHUNKS; vb += nblk) {
    if (vb < QGEMM_BLOCKS) {
      float* xlds = (float*)pool;  // 8 KB
      __syncthreads();             // protect pool reuse across iterations
#pragma unroll
      for (int p = 0; p < 8; ++p) {
        int idx = p * 256 + tid;
        int gidx = vb * (GEMM_ROWS * 64) + idx;
        xlds[idx] = (gidx < N_NODES * 64) ? x[gidx] : 0.f;
      }
      __syncthreads();
      {  // emit bf16 x
        int row = tid >> 3;
        int c0 = (tid & 7) * 8;
        int grow = vb * GEMM_ROWS + row;
        if (grow < N_NODES) {
          uint hu[4];
#pragma unroll
          for (int d2 = 0; d2 < 4; ++d2) {
            float v0 = xlds[row * 64 + c0 + 2 * d2];
            float v1 = xlds[row * 64 + c0 + 2 * d2 + 1];
            hu[d2] = (uint)bfrn(v0) | ((uint)bfrn(v1) << 16);
          }
          *(uint4*)(xhi + (size_t)grow * 64 + c0) =
              make_uint4(hu[0], hu[1], hu[2], hu[3]);
        }
      }
      const int c4 = tid & 63;
      const int h = c4 >> 4;
      const int f4 = c4 & 15;
      const int rg = (tid >> 6) * 8;
      const float4* Wv = (const float4*)Wt;
      float4 acc[8] = {};
      for (int g = 0; g < 64; ++g) {
        float4 w4 = Wv[(size_t)h * 1024 + g * 16 + f4];
#pragma unroll
        for (int r = 0; r < 8; ++r) {
          float a = xlds[(rg + r) * 64 + g];
          acc[r].x += a * w4.x; acc[r].y += a * w4.y;
          acc[r].z += a * w4.z; acc[r].w += a * w4.w;
        }
      }
      uint2* q_t2 = (uint2*)q_t;
#pragma unroll
      for (int r = 0; r < 8; ++r) {
        int row = vb * GEMM_ROWS + rg + r;
        if (row < N_NODES) {
          uint2 pk;
          pk.x = (uint)bfrn(acc[r].x) | ((uint)bfrn(acc[r].y) << 16);
          pk.y = (uint)bfrn(acc[r].z) | ((uint)bfrn(acc[r].w) << 16);
          q_t2[(size_t)row * 64 + c4] = pk;
        }
      }
    } else {
      int e = (vb - QGEMM_BLOCKS) * 256 + tid;
      if (e < N_EDGES) {
        int idx = offs2[dstv[e]].x + epos[e];
        csr2[idx] = make_int2(srcv[e], __float_as_int(ew[e]));
      }
    }
  }
  __threadfence();
  grid.sync();

  // ---- Phase E: aggregation (one wave per node, 16-edge tiles) ----
  {
    auto xt = (uint(*)[16][XT_STRIDE])pool;          // 9216 B
    auto plds = (float(*)[16][4])(pool + 9216);      // 1024 B
    const uint4* qt4 = (const uint4*)q_t;
    const uint4* xhi4 = (const uint4*)xhi;
    const int l15 = lane & 15;
    const int lg = lane >> 4;
    const int hq = l15 & 3;
    for (int vb = bid; vb < AGG_VB; vb += nblk) {
      const int node = vb * 4 + wave;
      const bf16x8_t Qa = as_bf16x8(qt4[(size_t)node * 32 + hq * 8 + lg]);
      const bf16x8_t Qb = as_bf16x8(qt4[(size_t)node * 32 + hq * 8 + 4 + lg]);
      const int2 o2 = offs2[node];
      const int s0 = o2.x;
      const int ntiles = o2.y;
      f32x4_t acc = {0.f, 0.f, 0.f, 0.f};
      float Lp = 0.f;
      for (int t = 0; t < ntiles; ++t) {
        const int k0 = s0 + t * 16;
        const int2 e2 = csr2[k0 + l15];
        const int j = e2.x;
        const float w = __int_as_float(e2.y);
        const uint4 ah0 = xhi4[(size_t)j * 8 + lg];
        const uint4 ah1 = xhi4[(size_t)j * 8 + 4 + lg];
        *(uint4*)&xt[wave][l15][4 * lg] = ah0;
        *(uint4*)&xt[wave][l15][16 + 4 * lg] = ah1;
        f32x4_t S = {0.f, 0.f, 0.f, 0.f};
        S = __builtin_amdgcn_mfma_f32_16x16x32_bf16(Qa, as_bf16x8(ah0), S, 0,
                                                    0, 0);
        S = __builtin_amdgcn_mfma_f32_16x16x32_bf16(Qb, as_bf16x8(ah1), S, 0,
                                                    0, 0);
        float p0 = exp2f(fmaxf(S[0], 0.2f * S[0])) * w;
        float p1 = exp2f(fmaxf(S[1], 0.2f * S[1])) * w;
        float p2 = exp2f(fmaxf(S[2], 0.2f * S[2])) * w;
        float p3 = exp2f(fmaxf(S[3], 0.2f * S[3])) * w;
        if (lg == 0)
          *(float4*)&plds[wave][l15][0] = make_float4(p0, p1, p2, p3);
#pragma unroll
        for (int e = 0; e < 16; ++e) {
          uint2 xw = *(const uint2*)&xt[wave][e][2 * l15];
          float pe = plds[wave][e][lg];
          acc[0] += pe * bflo(xw.x);
          acc[1] += pe * bfhi(xw.x);
          acc[2] += pe * bflo(xw.y);
          acc[3] += pe * bfhi(xw.y);
          Lp += pe;
        }
      }
      const float inv = 1.f / (Lp + 1e-16f);
      uint w0 = (uint)bfrn(acc[0] * inv) | ((uint)bfrn(acc[1] * inv) << 16);
      uint w1 = (uint)bfrn(acc[2] * inv) | ((uint)bfrn(acc[3] * inv) << 16);
      *(uint2*)(agg + (size_t)node * 256 + lg * 64 + l15 * 4) =
          make_uint2(w0, w1);
    }
  }
  __threadfence();
  grid.sync();

  // ---- Phase F: out = agg(bf16) @ blockdiag(Wlin) + bias, 16-node tiles ----
  {
    auto atile = (float4(*)[4][17])pool;  // [16 rows][hh][g4] = 17408 B
    const uint2* av = (const uint2*)agg;
    const int c4 = tid & 63;
    const int grp = tid >> 6;
    const int hh = c4 >> 4;
    const float4* Wv = (const float4*)Wlin;
    const float4 bv = ((const float4*)bias)[c4];
    for (int vb = bid; vb < OUT_VB; vb += nblk) {
      const int node0 = vb * 16;  // 3125*16 = 50000 exact
      __syncthreads();
#pragma unroll
      for (int p = 0; p < 4; ++p) {
        int idx = p * 256 + tid;
        int row = idx >> 6;
        int cc = idx & 63;
        uint2 u = av[(size_t)(node0 + row) * 64 + cc];
        float4 f;
        f.x = bflo(u.x); f.y = bfhi(u.x);
        f.z = bflo(u.y); f.w = bfhi(u.y);
        atile[row][cc >> 4][cc & 15] = f;
      }
      __syncthreads();
      float4 acc[4] = {};
      for (int g4 = 0; g4 < 16; ++g4) {
        float4 w0 = Wv[(size_t)(g4 * 4 + 0) * 64 + c4];
        float4 w1 = Wv[(size_t)(g4 * 4 + 1) * 64 + c4];
        float4 w2 = Wv[(size_t)(g4 * 4 + 2) * 64 + c4];
        float4 w3 = Wv[(size_t)(g4 * 4 + 3) * 64 + c4];
#pragma unroll
        for (int n = 0; n < 4; ++n) {
          float4 a = atile[grp * 4 + n][hh][g4];
          acc[n].x += a.x * w0.x + a.y * w1.x + a.z * w2.x + a.w * w3.x;
          acc[n].y += a.x * w0.y + a.y * w1.y + a.z * w2.y + a.w * w3.y;
          acc[n].z += a.x * w0.z + a.y * w1.z + a.z * w2.z + a.w * w3.z;
          acc[n].w += a.x * w0.w + a.y * w1.w + a.z * w2.w + a.w * w3.w;
        }
      }
#pragma unroll
      for (int n = 0; n < 4; ++n) {
        float4 o;
        o.x = acc[n].x + bv.x; o.y = acc[n].y + bv.y;
        o.z = acc[n].z + bv.z; o.w = acc[n].w + bv.w;
        ((float4*)out)[(size_t)(node0 + grp * 4 + n) * 64 + c4] = o;
      }
    }
  }
}

// ===========================================================================
// Fallback path: the verified R11 five-kernel pipeline (170.9 us).
// ===========================================================================
__global__ __launch_bounds__(256) void hist_kernel(
    const int* __restrict__ dst, int* __restrict__ deg, int* __restrict__ epos,
    const float* __restrict__ Watt, float* __restrict__ Wt) {
  int e = blockIdx.x * 256 + threadIdx.x;
  if (e < 16384) {
    int c = e & 63;
    int r = (e >> 6) & 63;
    int h = e >> 12;
    Wt[e] = Watt[c * 256 + h * 64 + r] * SCALE_FOLD;
  }
  if (e < N_EDGES) epos[e] = atomicAdd(&deg[dst[e]], 1);
}

__global__ __launch_bounds__(256) void qgemm_base_kernel(
    const float* __restrict__ x, const float* __restrict__ Wt,
    uint2* __restrict__ q_t2, ushort* __restrict__ xhi,
    const int* __restrict__ deg, int* __restrict__ cursor,
    int2* __restrict__ offs2, int2* __restrict__ csr2) {
  const int tid = threadIdx.x;
  if (blockIdx.x >= QGEMM_BLOCKS) {
    const int i = (blockIdx.x - QGEMM_BLOCKS) * 256 + tid;
    const int lane = tid & 63;
    const int d = (i < N_NODES) ? deg[i] : 0;
    const int nt = (d + 15) >> 4;
    const int pd = nt << 4;
    int incl = pd;
#pragma unroll
    for (int m = 1; m < 64; m <<= 1) {
      int u = __shfl_up(incl, m);
      if (lane >= m) incl += u;
    }
    int wbase = 0;
    if (lane == 63) wbase = atomicAdd(cursor, incl);
    wbase = __shfl(wbase, 63);
    const int base = wbase + incl - pd;
    if (i < N_NODES) {
      offs2[i] = make_int2(base, nt);
      for (int j = d; j < pd; ++j) csr2[base + j] = make_int2(0, 0);
    }
    return;
  }
  __shared__ float xlds[GEMM_ROWS * 64];
  const int blk = blockIdx.x;
#pragma unroll
  for (int p = 0; p < 8; ++p) {
    int idx = p * 256 + tid;
    int gidx = blk * (GEMM_ROWS * 64) + idx;
    xlds[idx] = (gidx < N_NODES * 64) ? x[gidx] : 0.f;
  }
  __syncthreads();
  {
    int row = tid >> 3;
    int c0 = (tid & 7) * 8;
    int grow = blk * GEMM_ROWS + row;
    if (grow < N_NODES) {
      uint hu[4];
#pragma unroll
      for (int d2 = 0; d2 < 4; ++d2) {
        float v0 = xlds[row * 64 + c0 + 2 * d2];
        float v1 = xlds[row * 64 + c0 + 2 * d2 + 1];
        hu[d2] = (uint)bfrn(v0) | ((uint)bfrn(v1) << 16);
      }
      *(uint4*)(xhi + (size_t)grow * 64 + c0) =
          make_uint4(hu[0], hu[1], hu[2], hu[3]);
    }
  }
  const int c4 = tid & 63;
  const int h = c4 >> 4;
  const int f4 = c4 & 15;
  const int rg = (tid >> 6) * 8;
  const float4* Wv = (const float4*)Wt;
  float4 acc[8] = {};
  for (int g = 0; g < 64; ++g) {
    float4 w4 = Wv[(size_t)h * 1024 + g * 16 + f4];
#pragma unroll
    for (int r = 0; r < 8; ++r) {
      float a = xlds[(rg + r) * 64 + g];
      acc[r].x += a * w4.x; acc[r].y += a * w4.y;
      acc[r].z += a * w4.z; acc[r].w += a * w4.w;
    }
  }
#pragma unroll
  for (int r = 0; r < 8; ++r) {
    int row = blk * GEMM_ROWS + rg + r;
    if (row < N_NODES) {
      uint2 pk;
      pk.x = (uint)bfrn(acc[r].x) | ((uint)bfrn(acc[r].y) << 16);
      pk.y = (uint)bfrn(acc[r].z) | ((uint)bfrn(acc[r].w) << 16);
      q_t2[(size_t)row * 64 + c4] = pk;
    }
  }
}

__global__ __launch_bounds__(256) void scatter_kernel(
    const int* __restrict__ src, const int* __restrict__ dst,
    const float* __restrict__ ew, const int2* __restrict__ offs2,
    const int* __restrict__ epos, int2* __restrict__ csr2) {
  int e = blockIdx.x * 256 + threadIdx.x;
  if (e >= N_EDGES) return;
  int idx = offs2[dst[e]].x + epos[e];
  csr2[idx] = make_int2(src[e], __float_as_int(ew[e]));
}

__global__ __launch_bounds__(256) void aggregate_kernel(
    const uint4* __restrict__ qt4, const uint4* __restrict__ xhi4,
    const int2* __restrict__ offs2, const int2* __restrict__ csr2,
    ushort* __restrict__ agg) {
  __shared__ __attribute__((aligned(16))) uint xt[4][16][XT_STRIDE];
  __shared__ __attribute__((aligned(16))) float plds[4][16][4];
  const int wave = threadIdx.x >> 6;
  const int node = blockIdx.x * 4 + wave;
  const int lane = threadIdx.x & 63;
  const int l15 = lane & 15;
  const int lg = lane >> 4;
  const int hq = l15 & 3;
  const bf16x8_t Qa = as_bf16x8(qt4[(size_t)node * 32 + hq * 8 + lg]);
  const bf16x8_t Qb = as_bf16x8(qt4[(size_t)node * 32 + hq * 8 + 4 + lg]);
  const int2 o2 = offs2[node];
  const int s0 = o2.x;
  const int ntiles = o2.y;
  f32x4_t acc = {0.f, 0.f, 0.f, 0.f};
  float Lp = 0.f;
  for (int t = 0; t < ntiles; ++t) {
    const int k0 = s0 + t * 16;
    const int2 e2 = csr2[k0 + l15];
    const int j = e2.x;
    const float w = __int_as_float(e2.y);
    const uint4 ah0 = xhi4[(size_t)j * 8 + lg];
    const uint4 ah1 = xhi4[(size_t)j * 8 + 4 + lg];
    *(uint4*)&xt[wave][l15][4 * lg] = ah0;
    *(uint4*)&xt[wave][l15][16 + 4 * lg] = ah1;
    f32x4_t S = {0.f, 0.f, 0.f, 0.f};
    S = __builtin_amdgcn_mfma_f32_16x16x32_bf16(Qa, as_bf16x8(ah0), S, 0, 0, 0);
    S = __builtin_amdgcn_mfma_f32_16x16x32_bf16(Qb, as_bf16x8(ah1), S, 0, 0, 0);
    float p0 = exp2f(fmaxf(S[0], 0.2f * S[0])) * w;
    float p1 = exp2f(fmaxf(S[1], 0.2f * S[1])) * w;
    float p2 = exp2f(fmaxf(S[2], 0.2f * S[2])) * w;
    float p3 = exp2f(fmaxf(S[3], 0.2f * S[3])) * w;
    if (lg == 0) *(float4*)&plds[wave][l15][0] = make_float4(p0, p1, p2, p3);
#pragma unroll
    for (int e = 0; e < 16; ++e) {
      uint2 xw = *(const uint2*)&xt[wave][e][2 * l15];
      float pe = plds[wave][e][lg];
      acc[0] += pe * bflo(xw.x);
      acc[1] += pe * bfhi(xw.x);
      acc[2] += pe * bflo(xw.y);
      acc[3] += pe * bfhi(xw.y);
      Lp += pe;
    }
  }
  const float inv = 1.f / (Lp + 1e-16f);
  uint w0 = (uint)bfrn(acc[0] * inv) | ((uint)bfrn(acc[1] * inv) << 16);
  uint w1 = (uint)bfrn(acc[2] * inv) | ((uint)bfrn(acc[3] * inv) << 16);
  *(uint2*)(agg + (size_t)node * 256 + lg * 64 + l15 * 4) = make_uint2(w0, w1);
}

__global__ __launch_bounds__(256) void out_gemm_kernel(
    const ushort* __restrict__ agg, const float* __restrict__ Wlin,
    const float* __restrict__ bias, float* __restrict__ out) {
  __shared__ float4 atile[AGG_NODES][4][17];
  const int tid = threadIdx.x;
  const int node0 = blockIdx.x * AGG_NODES;
  const uint2* av = (const uint2*)agg;
#pragma unroll
  for (int p = 0; p < 8; ++p) {
    int idx = p * 256 + tid;
    int row = idx >> 6;
    int cc = idx & 63;
    if (node0 + row < N_NODES) {
      uint2 u = av[(size_t)(node0 + row) * 64 + cc];
      float4 f;
      f.x = bflo(u.x); f.y = bfhi(u.x);
      f.z = bflo(u.y); f.w = bfhi(u.y);
      atile[row][cc >> 4][cc & 15] = f;
    }
  }
  __syncthreads();
  const int c4 = tid & 63;
  const int ns = tid >> 6;
  const int hh = c4 >> 4;
  const float4* Wv = (const float4*)Wlin;
  float4 acc[8] = {};
  for (int g4 = 0; g4 < 16; ++g4) {
    float4 w0 = Wv[(size_t)(g4 * 4 + 0) * 64 + c4];
    float4 w1 = Wv[(size_t)(g4 * 4 + 1) * 64 + c4];
    float4 w2 = Wv[(size_t)(g4 * 4 + 2) * 64 + c4];
    float4 w3 = Wv[(size_t)(g4 * 4 + 3) * 64 + c4];
#pragma unroll
    for (int n = 0; n < 8; ++n) {
      float4 a = atile[ns * 8 + n][hh][g4];
      acc[n].x += a.x * w0.x + a.y * w1.x + a.z * w2.x + a.w * w3.x;
      acc[n].y += a.x * w0.y + a.y * w1.y + a.z * w2.y + a.w * w3.y;
      acc[n].z += a.x * w0.z + a.y * w1.z + a.z * w2.z + a.w * w3.z;
      acc[n].w += a.x * w0.w + a.y * w1.w + a.z * w2.w + a.w * w3.w;
    }
  }
  float4 bv = ((const float4*)bias)[c4];
#pragma unroll
  for (int n = 0; n < 8; ++n) {
    int node = node0 + ns * 8 + n;
    if (node < N_NODES) {
      float4 o;
      o.x = acc[n].x + bv.x; o.y = acc[n].y + bv.y;
      o.z = acc[n].z + bv.z; o.w = acc[n].w + bv.w;
      ((float4*)out)[(size_t)node * 64 + c4] = o;
    }
  }
}

// ---------------------------------------------------------------------------
extern "C" void kernel_launch(void* const* d_in, const int* in_sizes, int n_in,
                              void* d_out, int out_size, void* d_ws,
                              size_t ws_size, hipStream_t stream) {
  (void)in_sizes; (void)n_in; (void)out_size; (void)ws_size;
  const float* x    = (const float*)d_in[0];
  const int*   ei   = (const int*)d_in[1];
  const float* ew   = (const float*)d_in[2];
  const float* Wlin = (const float*)d_in[3];
  const float* Watt = (const float*)d_in[4];
  const float* bias = (const float*)d_in[5];
  float* out = (float*)d_out;

  const int* srcv = ei;
  const int* dstv = ei + N_EDGES;

  char* ws = (char*)d_ws;
  size_t off = 0;
  auto alloc = [&](size_t bytes) {
    void* p = ws + off;
    off += (bytes + 255) & ~(size_t)255;
    return p;
  };
  ushort* q_t   = (ushort*)alloc((size_t)N_NODES * 256 * 2);  // 25.6 MB
  ushort* agg   = (ushort*)alloc((size_t)N_NODES * 256 * 2);  // 25.6 MB
  ushort* xhi   = (ushort*)alloc((size_t)N_NODES * 64 * 2);   // 6.4 MB
  int2*   offs2 = (int2*)alloc((size_t)N_NODES * 8);          // 0.4 MB
  int2*   csr2  = (int2*)alloc((size_t)PAD_EDGES * 8);        // 12.4 MB
  char* aggc = (char*)agg;
  int*   deg    = (int*)aggc;
  int*   cursor = (int*)(aggc + N_NODES * 4);
  int*   epos   = (int*)(aggc + 256 * 1024);
  float* Wt     = (float*)(aggc + 4 * 1024 * 1024);

  // ---- try cooperative mega-kernel, sized from measured occupancy ----
  int maxBlocksPerCU = 0;
  hipError_t qerr = hipOccupancyMaxActiveBlocksPerMultiprocessor(
      &maxBlocksPerCU, (const void*)mega_kernel, 256, 0);
  bool coop_done = false;
  if (qerr == hipSuccess && maxBlocksPerCU >= 1) {
    int gridsz = maxBlocksPerCU * NUM_CU;
    if (gridsz > GRID_WANT) gridsz = GRID_WANT;
    if (gridsz >= 256) {  // phases assume grid >= BASE_BLOCKS (196)
      void* args[] = {&x,    &srcv, &dstv, &ew,    &Wlin, &bias,   &Watt,
                      &out,  &q_t,  &xhi,  &agg,   &offs2, &csr2,  &deg,
                      &cursor, &epos, &Wt};
      hipError_t lerr = hipLaunchCooperativeKernel(
          (const void*)mega_kernel, dim3(gridsz), dim3(256), args, 0, stream);
      coop_done = (lerr == hipSuccess);
    }
  }
  if (coop_done) return;

  // ---- fallback: verified 5-kernel pipeline ----
  hipMemsetAsync(deg, 0, (size_t)(N_NODES + 64) * 4, stream);
  hist_kernel<<<(N_EDGES + 255) / 256, 256, 0, stream>>>(dstv, deg, epos,
                                                         Watt, Wt);
  qgemm_base_kernel<<<QGEMM_BLOCKS + BASE_BLOCKS, 256, 0, stream>>>(
      x, Wt, (uint2*)q_t, xhi, deg, cursor, offs2, csr2);
  scatter_kernel<<<(N_EDGES + 255) / 256, 256, 0, stream>>>(
      srcv, dstv, ew, offs2, epos, csr2);
  aggregate_kernel<<<N_NODES / 4, 256, 0, stream>>>(
      (const uint4*)q_t, (const uint4*)xhi, offs2, csr2, agg);
  out_gemm_kernel<<<(N_NODES + AGG_NODES - 1) / AGG_NODES, 256, 0, stream>>>(
      agg, Wlin, bias, out);
}